// Round 1
// baseline (412.066 us; speedup 1.0000x reference)
//
#include <hip/hip_runtime.h>

// PrimaryCaps on MI355X: stride-2 conv(256->256, 9x9) as implicit GEMM in bf16 MFMA,
// + bias + capsule squash (groups of 8 along width).
//
// Pipeline:
//   1) prep_w_k : W f32 [oc][ic][9][9]  -> Wb bf16 [oc][kh*9+kw][ic]      (10.6 MB)
//   2) prep_x_k : x f32 NCHW [64][256][40][40] -> Xt bf16 NHWC [b][ih][iw][ic] (52.4 MB)
//   3) gemm_k   : C[oc][n] = sum_k Wb[oc][k] * Xt[pix(n,khw)][ic],  K=(khw,ic)=20736
//                 128x128 tile, BK=64, 4 waves, mfma 16x16x32 bf16, K-split S via blockIdx.z
//                 LDS linear (global_load_lds w=16) with pre-swizzled global source (slot^row&7)
//   4) finish_k : sum K-splits + bias + squash -> d_out NCHW f32

typedef __attribute__((ext_vector_type(8))) short bf16x8;
typedef __attribute__((ext_vector_type(4))) float f32x4;

static __device__ __forceinline__ unsigned short f2bf(float f) {
  unsigned u = __builtin_bit_cast(unsigned, f);
  u += 0x7FFFu + ((u >> 16) & 1u);   // RNE; inputs finite
  return (unsigned short)(u >> 16);
}

static __device__ __forceinline__ void gll16(const void* g, void* l) {
  typedef __attribute__((address_space(1))) const unsigned char AS1;
  typedef __attribute__((address_space(3))) unsigned char AS3;
  __builtin_amdgcn_global_load_lds((AS1*)g, (AS3*)l, 16, 0, 0);
}

// ---- prep W: [256][256][9][9] f32 -> [oc][khw][ic] bf16 ----
__global__ __launch_bounds__(256) void prep_w_k(const float* __restrict__ W,
                                                unsigned short* __restrict__ Wb) {
  __shared__ float t[5184];                      // [ic64][khw81]
  int bid = blockIdx.x;                          // 256 oc * 4 ic-tiles
  int oc = bid >> 2, ict = bid & 3;
  const float* src = W + ((size_t)oc * 256 + (size_t)ict * 64) * 81;
  for (int i = threadIdx.x; i < 5184; i += 256) t[i] = src[i];  // fully coalesced
  __syncthreads();
  unsigned short* dst = Wb + (size_t)oc * 20736 + ict * 64;
  for (int i = threadIdx.x; i < 5184; i += 256) {
    int khw = i >> 6, ic = i & 63;
    dst[(size_t)khw * 256 + ic] = f2bf(t[ic * 81 + khw]);  // stride-81 LDS read: conflict-free
  }
}

// ---- prep X: NCHW f32 -> NHWC bf16 ----
__global__ __launch_bounds__(256) void prep_x_k(const float* __restrict__ x,
                                                unsigned short* __restrict__ Xt) {
  __shared__ float t[64][41];                    // +1 pad: 2-way max on transpose read
  int bid = blockIdx.x;                          // 64 b * 40 ih * 4 ic-tiles
  int ict = bid & 3;
  int ih = (bid >> 2) % 40;
  int b  = bid / 160;
  const float* src = x + (((size_t)(b * 256 + ict * 64) * 40) + ih) * 40;
  for (int i = threadIdx.x; i < 2560; i += 256) {
    int ic = i / 40, iw = i - ic * 40;
    t[ic][iw] = src[(size_t)ic * 1600 + iw];
  }
  __syncthreads();
  unsigned short* dst = Xt + ((size_t)(b * 40 + ih) * 40) * 256 + ict * 64;
  for (int i = threadIdx.x; i < 1280; i += 256) {
    int iw = i >> 5, icp = i & 31;
    unsigned lo = f2bf(t[icp * 2][iw]);
    unsigned hi = f2bf(t[icp * 2 + 1][iw]);
    *(unsigned*)(dst + (size_t)iw * 256 + icp * 2) = (hi << 16) | lo;  // 4B/lane contiguous
  }
}

// ---- implicit GEMM ----
// A = Wb [M=256][K=20736], B = Xt gathered [N=16384][K], D = C[oc][n], n = b*256+oh*16+ow.
// Block: 128(M) x 128(N), BK=64 (one (kh,kw), 64 consecutive ic). Grid (128 n-tiles, 2 m-tiles, S splits).
__global__ __launch_bounds__(256) void gemm_k(const unsigned short* __restrict__ Wb,
                                              const unsigned short* __restrict__ Xt,
                                              float* __restrict__ Cp, int kts) {
  __shared__ __align__(16) short Asm[8192];      // [128 m][64 k] bf16, slot-swizzled
  __shared__ __align__(16) short Bsm[8192];      // [128 n][64 k] bf16, slot-swizzled
  const int tid = threadIdx.x;
  const int l = tid & 63, w = tid >> 6;
  const int wm = w >> 1, wn = w & 1;
  const int nc = blockIdx.x, mr = blockIdx.y, sz = blockIdx.z;
  const int b = nc >> 1, ohb = (nc & 1) << 3;    // n-tile = fixed batch, 8 oh rows, all 16 ow
  const int ocb = mr << 7;

  // staging geometry: per global_load_lds instr, 64 lanes = 8 rows x 8 slots of 16B (1 KiB)
  const int lrow  = l >> 3;                      // row within 8-row group
  const int lslot = l & 7;                       // 16B slot within row
  const int chunk = ((lslot ^ lrow) << 3);       // swizzled source k-offset (elements); row&7==lrow

  unsigned aoff[4], boff[4];
#pragma unroll
  for (int i = 0; i < 4; ++i) {
    int rloc = ((w * 4 + i) << 3) + lrow;        // 0..127 (row of the tile this lane stages)
    aoff[i] = (unsigned)(ocb + rloc) * 20736u + (unsigned)chunk;
    int ohl = rloc >> 4, owl = rloc & 15;
    boff[i] = (unsigned)(((b * 40 + 2 * (ohb + ohl)) * 40) + 2 * owl) * 256u + (unsigned)chunk;
  }

  const int fr = l & 15;                         // fragment row/col index
  const int kq = l >> 4;                         // k-quarter
  int arow[4], brow[4];
#pragma unroll
  for (int i = 0; i < 4; ++i) {
    arow[i] = wm * 64 + i * 16 + fr;
    brow[i] = wn * 64 + i * 16 + fr;
  }

  f32x4 acc[4][4];
#pragma unroll
  for (int mi = 0; mi < 4; ++mi)
#pragma unroll
    for (int ni = 0; ni < 4; ++ni) acc[mi][ni] = (f32x4){0.f, 0.f, 0.f, 0.f};

  const int kt0 = sz * kts, kt1 = kt0 + kts;
  for (int kt = kt0; kt < kt1; ++kt) {
    const int khw = kt >> 2, ict = kt & 3;       // k-tile = (kh,kw) fixed, 64 ic
    const int kh = khw / 9, kw = khw - kh * 9;
    const unsigned ka = (unsigned)kt << 6;                                 // k elem offset in W row
    const unsigned kb = (unsigned)((kh * 40 + kw) << 8) + (unsigned)(ict << 6);  // pixel+ic offset in Xt
#pragma unroll
    for (int i = 0; i < 4; ++i) {
      gll16(Wb + aoff[i] + ka, Asm + ((w * 4 + i) << 9));
      gll16(Xt + boff[i] + kb, Bsm + ((w * 4 + i) << 9));
    }
    __syncthreads();                             // compiler drains vmcnt before s_barrier
#pragma unroll
    for (int kk = 0; kk < 2; ++kk) {
      const int kc = (kk << 2) + kq;
      bf16x8 af[4], bg[4];
#pragma unroll
      for (int i = 0; i < 4; ++i) {
        af[i] = *(const bf16x8*)(Asm + (arow[i] << 6) + ((kc ^ (arow[i] & 7)) << 3));
        bg[i] = *(const bf16x8*)(Bsm + (brow[i] << 6) + ((kc ^ (brow[i] & 7)) << 3));
      }
#pragma unroll
      for (int mi = 0; mi < 4; ++mi)
#pragma unroll
        for (int ni = 0; ni < 4; ++ni)
          acc[mi][ni] = __builtin_amdgcn_mfma_f32_16x16x32_bf16(af[mi], bg[ni], acc[mi][ni], 0, 0, 0);
    }
    __syncthreads();
  }

  // epilogue: partial C -> ws.  C/D layout: col = l&15, row = (l>>4)*4 + reg   [m89-verified]
  float* Co = Cp + (size_t)sz * 4194304;
  const int nbase = nc << 7;
#pragma unroll
  for (int mi = 0; mi < 4; ++mi) {
#pragma unroll
    for (int ni = 0; ni < 4; ++ni) {
      int ocr = ocb + wm * 64 + mi * 16 + kq * 4;
      int n = nbase + wn * 64 + ni * 16 + fr;
#pragma unroll
      for (int r = 0; r < 4; ++r)
        Co[(size_t)(ocr + r) * 16384 + n] = acc[mi][ni][r];
    }
  }
}

// ---- reduce splits + bias + squash ----
__global__ __launch_bounds__(256) void finish_k(const float* __restrict__ Cp,
                                                const float* __restrict__ bias,
                                                float* __restrict__ out, int S) {
  int cap = blockIdx.x * 256 + threadIdx.x;      // 524288 capsules
  int b = cap >> 13;
  int flat = (cap & 8191) << 3;                  // index in per-batch CHW flattening
  int oc = flat >> 8;
  size_t cbase = (size_t)oc * 16384 + (size_t)b * 256 + (size_t)(flat & 255);
  float v[8];
#pragma unroll
  for (int i = 0; i < 8; ++i) v[i] = 0.f;
  for (int s = 0; s < S; ++s) {
    const float4* p = (const float4*)(Cp + (size_t)s * 4194304 + cbase);
    float4 a0 = p[0], a1 = p[1];
    v[0] += a0.x; v[1] += a0.y; v[2] += a0.z; v[3] += a0.w;
    v[4] += a1.x; v[5] += a1.y; v[6] += a1.z; v[7] += a1.w;
  }
  float bb = bias[oc];
  float sq = 0.f;
#pragma unroll
  for (int i = 0; i < 8; ++i) { v[i] += bb; sq += v[i] * v[i]; }
  float scale = sq / ((1.0f + sq) * sqrtf(sq + 1e-8f));
  float4 o0 = make_float4(v[0] * scale, v[1] * scale, v[2] * scale, v[3] * scale);
  float4 o1 = make_float4(v[4] * scale, v[5] * scale, v[6] * scale, v[7] * scale);
  float4* q = (float4*)(out + (size_t)cap * 8);
  q[0] = o0; q[1] = o1;
}

extern "C" void kernel_launch(void* const* d_in, const int* in_sizes, int n_in,
                              void* d_out, int out_size, void* d_ws, size_t ws_size,
                              hipStream_t stream) {
  const float* x    = (const float*)d_in[0];
  const float* W    = (const float*)d_in[1];
  const float* bias = (const float*)d_in[2];
  float* out = (float*)d_out;
  char* ws = (char*)d_ws;

  unsigned short* Xt = (unsigned short*)ws;                   // 52,428,800 B
  unsigned short* Wb = (unsigned short*)(ws + 52428800ull);   // 10,616,832 B
  float*          Cp = (float*)(ws + 63045632ull);            // S * 16,777,216 B

  const size_t slice = 16777216ull;
  int S = 1;
  if (ws_size >= 63045632ull + 4 * slice) S = 4;
  else if (ws_size >= 63045632ull + 2 * slice) S = 2;

  prep_x_k<<<10240, 256, 0, stream>>>(x, Xt);
  prep_w_k<<<1024, 256, 0, stream>>>(W, Wb);
  gemm_k<<<dim3(128, 2, S), 256, 0, stream>>>(Wb, Xt, Cp, 324 / S);
  finish_k<<<2048, 256, 0, stream>>>(Cp, bias, out, S);
}

// Round 5
// 341.095 us; speedup vs baseline: 1.2081x; 1.2081x over previous
//
#include <hip/hip_runtime.h>

// PrimaryCaps on MI355X: stride-2 conv(256->256, 9x9) as implicit GEMM in bf16 MFMA,
// + bias + capsule squash.
//
// R2 (3rd resubmit; three broker timeouts in a row, kernel has never run):
// GEMM as 256x256-tile, 8-wave, double-buffered-LDS, counted-vmcnt schedule
// (T3+T4), T2 XOR-swizzle, T5 setprio. Raw s_barrier + asm s_waitcnt (never
// vmcnt(0) in steady state) so prefetch loads stay in flight across the
// barrier -- the m97-ceiling breaker per learn_hip m218.
//
//   1) prep_k   : merged  W f32 OIHW -> Wb bf16 [oc][khw][ic]   and
//                         x f32 NCHW -> Xt bf16 NHWC
//   2) gemm_k   : C[oc][n] = sum_k Wb[oc][k] * Xt[pix(n,khw)][ic], K=20736,
//                 BM=BN=256, BK=64, 8 waves (2M x 4N), per-wave C 128x64,
//                 K-split S via blockIdx.z (grid 64 x 1 x S = 256 blocks at S=4)
//   3) finish_k : sum K-splits + bias + squash -> d_out NCHW f32

typedef __attribute__((ext_vector_type(8))) short bf16x8;
typedef __attribute__((ext_vector_type(4))) float f32x4;

#define SBAR __builtin_amdgcn_sched_barrier(0)
#define HBAR __builtin_amdgcn_s_barrier()
#define CFEN asm volatile("" ::: "memory")

static __device__ __forceinline__ unsigned short f2bf(float f) {
  unsigned u = __builtin_bit_cast(unsigned, f);
  u += 0x7FFFu + ((u >> 16) & 1u);   // RNE; inputs finite
  return (unsigned short)(u >> 16);
}

static __device__ __forceinline__ void gll16(const void* g, void* l) {
  typedef __attribute__((address_space(1))) const unsigned char AS1;
  typedef __attribute__((address_space(3))) unsigned char AS3;
  __builtin_amdgcn_global_load_lds((AS1*)g, (AS3*)l, 16, 0, 0);
}

// ---- merged prep: blocks [0,10240) transpose x, [10240,11264) transpose W ----
__global__ __launch_bounds__(256) void prep_k(const float* __restrict__ x,
                                              const float* __restrict__ W,
                                              unsigned short* __restrict__ Xt,
                                              unsigned short* __restrict__ Wb) {
  __shared__ float t[5184];
  int bx = blockIdx.x;
  if (bx < 10240) {
    // x: NCHW [64][256][40][40] f32 -> Xt NHWC [b][ih][iw][ic] bf16
    int ict = bx & 3;
    int ih = (bx >> 2) % 40;
    int b  = bx / 160;
    const float4* src4 = (const float4*)(x + ((size_t)(b * 256 + ict * 64) * 40 + ih) * 40);
    for (int i = threadIdx.x; i < 640; i += 256) {
      int ic = i / 10, q = i - ic * 10;
      float4 v = src4[ic * 400 + q];           // row stride 1600 f32 = 400 float4
      float* tr = t + ic * 41 + q * 4;         // [64][41]: pad -> 2-way max on read
      tr[0] = v.x; tr[1] = v.y; tr[2] = v.z; tr[3] = v.w;
    }
    __syncthreads();
    unsigned short* dst = Xt + ((size_t)(b * 40 + ih) * 40) * 256 + ict * 64;
    for (int i = threadIdx.x; i < 1280; i += 256) {
      int iw = i >> 5, icp = i & 31;
      unsigned lo = f2bf(t[(icp * 2) * 41 + iw]);
      unsigned hi = f2bf(t[(icp * 2 + 1) * 41 + iw]);
      *(unsigned*)(dst + (size_t)iw * 256 + icp * 2) = (hi << 16) | lo;
    }
  } else {
    // W: [256][256][9][9] f32 -> Wb [oc][khw][ic] bf16
    int bid = bx - 10240;
    int oc = bid >> 2, ict = bid & 3;
    const float* src = W + ((size_t)oc * 256 + (size_t)ict * 64) * 81;
    for (int i = threadIdx.x; i < 5184; i += 256) t[i] = src[i];
    __syncthreads();
    unsigned short* dst = Wb + (size_t)oc * 20736 + ict * 64;
    for (int i = threadIdx.x; i < 5184; i += 256) {
      int khw = i >> 6, ic = i & 63;
      dst[(size_t)khw * 256 + ic] = f2bf(t[ic * 81 + khw]);  // stride-81: conflict-free
    }
  }
}

// ---- implicit GEMM, 256^2 tile, counted-vmcnt double-buffer ----
// LDS: A[2][256][64] bf16 @ short-offset 0, B[2][256][64] @ 32768. 128 KiB.
// Wave w (0..7): wm=w>>2, wn=w&3; owns C rows [wm*128,+128) x cols [wn*64,+64).
// Staging: per K-tile 8 gll16/wave; lane l -> row w*16+(l>>3)(+8 for 2nd instr),
// slot l&7, global source k-chunk pre-swizzled by slot^(row&7) (involution, r21).
__global__ __launch_bounds__(512, 2) void gemm_k(const unsigned short* __restrict__ Wb,
                                                 const unsigned short* __restrict__ Xt,
                                                 float* __restrict__ Cp, int kts) {
  __shared__ __align__(16) short LDS[65536];
  const int tid = threadIdx.x;
  const int l = tid & 63, w = tid >> 6;
  const int wm = w >> 2, wn = w & 3;
  const int nc = blockIdx.x, sz = blockIdx.z;   // nc = batch (256 outputs each)

  const int lrow = l >> 3, lslot = l & 7;
  const int chunk = (lslot ^ lrow) << 3;        // pre-swizzled k-offset (shorts)

  unsigned aoffA[2], boffB[2];
  int dstA[2], dstB[2];
#pragma unroll
  for (int h = 0; h < 2; ++h) {
    int srow = h * 128 + w * 16 + lrow;         // tile row this lane stages
    aoffA[h] = (unsigned)srow * 20736u + (unsigned)chunk;
    int oh = h * 8 + w, ow = lrow;              // srow>>4, srow&15
    boffB[h] = (unsigned)((nc * 40 + 2 * oh) * 40 + 2 * ow) * 256u + (unsigned)chunk;
    dstA[h] = (h * 128 + w * 16) << 6;          // shorts
    dstB[h] = 32768 + dstA[h];
  }

  const int fr = l & 15, kq = l >> 4, sw = fr & 7;
  const int arow0 = wm * 128 + fr;              // + mi*16
  const int brow0 = wn * 64 + fr;               // + ni*16

  f32x4 acc[8][4];
#pragma unroll
  for (int mi = 0; mi < 8; ++mi)
#pragma unroll
    for (int ni = 0; ni < 4; ++ni) acc[mi][ni] = (f32x4){0.f, 0.f, 0.f, 0.f};

  const int kt0 = sz * kts, nkt = kts;

  // prologue: stage tile kt0 into buffer 0
  {
    const unsigned ka0 = (unsigned)kt0 << 6;
    const int khw0 = kt0 >> 2, ict0 = kt0 & 3;
    const int kh0 = khw0 / 9, kw0 = khw0 - kh0 * 9;
    const unsigned kb0 = (unsigned)((kh0 * 40 + kw0) << 8) + (unsigned)(ict0 << 6);
#pragma unroll
    for (int h = 0; h < 2; ++h) {
      gll16(Wb + aoffA[h] + ka0, LDS + dstA[h]);
      gll16(Wb + aoffA[h] + ka0 + 8u * 20736u, LDS + dstA[h] + 512);
      gll16(Xt + boffB[h] + kb0, LDS + dstB[h]);
      gll16(Xt + boffB[h] + kb0 + 4096u, LDS + dstB[h] + 512);
    }
  }

#define DO_PHASE(P)                                                              \
  {                                                                              \
    bf16x8 af[2][2];                                                             \
    _Pragma("unroll") for (int j = 0; j < 2; ++j)                                \
    _Pragma("unroll") for (int kk = 0; kk < 2; ++kk) {                           \
      int row = arow0 + (2 * (P) + j) * 16;                                      \
      int kc = kk * 4 + kq;                                                      \
      af[j][kk] = *(const bf16x8*)(LDS + buf + (row << 6) + ((kc ^ sw) << 3));   \
    }                                                                            \
    __builtin_amdgcn_s_setprio(1);                                               \
    _Pragma("unroll") for (int j = 0; j < 2; ++j)                                \
    _Pragma("unroll") for (int ni = 0; ni < 4; ++ni)                             \
    _Pragma("unroll") for (int kk = 0; kk < 2; ++kk)                             \
      acc[2 * (P) + j][ni] = __builtin_amdgcn_mfma_f32_16x16x32_bf16(            \
          af[j][kk], bg[ni][kk], acc[2 * (P) + j][ni], 0, 0, 0);                 \
    __builtin_amdgcn_s_setprio(0);                                               \
  }

  for (int t = 0; t < nkt; ++t) {
    const int kt = kt0 + t;
    const int buf = (t & 1) << 14;              // short offset of compute buffer
    const int nb = buf ^ 16384;                 // staging buffer
    const unsigned kaN = (unsigned)(kt + 1) << 6;
    const int ktn = kt + 1;
    const int khwN = ktn >> 2, ictN = ktn & 3;
    const int khN = khwN / 9, kwN = khwN - khN * 9;
    const unsigned kbN = (unsigned)((khN * 40 + kwN) << 8) + (unsigned)(ictN << 6);
    const bool more = (t + 1 < nkt);

    // barrier1: every wave done ds_reading buf^1 (tile t-1) before we overwrite it
    SBAR; HBAR; CFEN;
    if (more) {                                 // burst-issue tile t+1 (8 vmem ops)
#pragma unroll
      for (int h = 0; h < 2; ++h) {
        gll16(Wb + aoffA[h] + kaN, LDS + nb + dstA[h]);
        gll16(Wb + aoffA[h] + kaN + 8u * 20736u, LDS + nb + dstA[h] + 512);
        gll16(Xt + boffB[h] + kbN, LDS + nb + dstB[h]);
        gll16(Xt + boffB[h] + kbN + 4096u, LDS + nb + dstB[h] + 512);
      }
      SBAR;
      asm volatile("s_waitcnt vmcnt(8)" ::: "memory");  // tile-t ops done; t+1 in flight
    } else {
      SBAR;
      asm volatile("s_waitcnt vmcnt(0)" ::: "memory");
    }
    HBAR; CFEN; SBAR;                           // barrier2: tile t fully staged (all waves)

    bf16x8 bg[4][2];                            // B frags cached for all 4 phases
#pragma unroll
    for (int ni = 0; ni < 4; ++ni)
#pragma unroll
      for (int kk = 0; kk < 2; ++kk) {
        int row = brow0 + ni * 16;
        int kc = kk * 4 + kq;
        bg[ni][kk] = *(const bf16x8*)(LDS + 32768 + buf + (row << 6) + ((kc ^ sw) << 3));
      }

    DO_PHASE(0)
    DO_PHASE(1)
    DO_PHASE(2)
    DO_PHASE(3)
  }
#undef DO_PHASE

  // epilogue: partial C -> ws.  C/D layout: col = l&15, row = (l>>4)*4 + reg  [m89]
  float* Co = Cp + (size_t)sz * 4194304;
#pragma unroll
  for (int mi = 0; mi < 8; ++mi) {
#pragma unroll
    for (int ni = 0; ni < 4; ++ni) {
      int oc = wm * 128 + mi * 16 + kq * 4;
      int n = (nc << 8) + wn * 64 + ni * 16 + fr;
#pragma unroll
      for (int r = 0; r < 4; ++r)
        Co[(size_t)(oc + r) * 16384 + n] = acc[mi][ni][r];
    }
  }
}

// ---- reduce splits + bias + squash ----
__global__ __launch_bounds__(256) void finish_k(const float* __restrict__ Cp,
                                                const float* __restrict__ bias,
                                                float* __restrict__ out, int S) {
  int cap = blockIdx.x * 256 + threadIdx.x;     // 524288 capsules
  int b = cap >> 13;
  int flat = (cap & 8191) << 3;                 // within-batch CHW index
  int oc = flat >> 8;
  size_t cbase = (size_t)oc * 16384 + (size_t)b * 256 + (size_t)(flat & 255);
  float v[8];
#pragma unroll
  for (int i = 0; i < 8; ++i) v[i] = 0.f;
  for (int s = 0; s < S; ++s) {
    const float4* p = (const float4*)(Cp + (size_t)s * 4194304 + cbase);
    float4 a0 = p[0], a1 = p[1];
    v[0] += a0.x; v[1] += a0.y; v[2] += a0.z; v[3] += a0.w;
    v[4] += a1.x; v[5] += a1.y; v[6] += a1.z; v[7] += a1.w;
  }
  float bb = bias[oc];
  float sq = 0.f;
#pragma unroll
  for (int i = 0; i < 8; ++i) { v[i] += bb; sq += v[i] * v[i]; }
  float scale = sq / ((1.0f + sq) * sqrtf(sq + 1e-8f));
  float4 o0 = make_float4(v[0] * scale, v[1] * scale, v[2] * scale, v[3] * scale);
  float4 o1 = make_float4(v[4] * scale, v[5] * scale, v[6] * scale, v[7] * scale);
  float4* q = (float4*)(out + (size_t)cap * 8);
  q[0] = o0; q[1] = o1;
}

extern "C" void kernel_launch(void* const* d_in, const int* in_sizes, int n_in,
                              void* d_out, int out_size, void* d_ws, size_t ws_size,
                              hipStream_t stream) {
  const float* x    = (const float*)d_in[0];
  const float* W    = (const float*)d_in[1];
  const float* bias = (const float*)d_in[2];
  float* out = (float*)d_out;
  char* ws = (char*)d_ws;

  unsigned short* Xt = (unsigned short*)ws;                   // 52,428,800 B
  unsigned short* Wb = (unsigned short*)(ws + 52428800ull);   // 10,616,832 B
  float*          Cp = (float*)(ws + 63045632ull);            // S * 16,777,216 B

  const size_t slice = 16777216ull;
  int S = 1;
  if (ws_size >= 63045632ull + 4 * slice) S = 4;
  else if (ws_size >= 63045632ull + 2 * slice) S = 2;

  prep_k<<<11264, 256, 0, stream>>>(x, W, Xt, Wb);
  gemm_k<<<dim3(64, 1, S), 512, 0, stream>>>(Wb, Xt, Cp, 324 / S);
  finish_k<<<2048, 256, 0, stream>>>(Cp, bias, out, S);
}